// Round 1
// baseline (3361.455 us; speedup 1.0000x reference)
//
#include <hip/hip_runtime.h>

#define D 64
#define NG 64

// Monotonic float<->uint encode for atomicMax-based segment max.
__device__ __forceinline__ unsigned encf(float f){
  unsigned u = __float_as_uint(f);
  return (u & 0x80000000u) ? ~u : (u | 0x80000000u);
}
__device__ __forceinline__ float decf(unsigned u){
  return (u & 0x80000000u) ? __uint_as_float(u & 0x7FFFFFFFu) : __uint_as_float(~u);
}

// Fused x@{Wq,Wk,Wv,Ws} + bias. One wave per row; weights staged in LDS.
__global__ __launch_bounds__(256) void k_linear4(
    const float* __restrict__ x,
    const float* __restrict__ Wq, const float* __restrict__ bq,
    const float* __restrict__ Wk, const float* __restrict__ bk,
    const float* __restrict__ Wv, const float* __restrict__ bv,
    const float* __restrict__ Ws, const float* __restrict__ bs,
    float* __restrict__ q, float* __restrict__ k, float* __restrict__ v,
    float* __restrict__ agg, int N)
{
  __shared__ float W[4][D*D];   // 64 KiB
  for (int i = threadIdx.x; i < D*D; i += 256){
    W[0][i]=Wq[i]; W[1][i]=Wk[i]; W[2][i]=Wv[i]; W[3][i]=Ws[i];
  }
  __syncthreads();
  const int lane = threadIdx.x & 63;
  const int wid  = threadIdx.x >> 6;
  const float bqv=bq[lane], bkv=bk[lane], bvv=bv[lane], bsv=bs[lane];
  const int wg = blockIdx.x*4 + wid;
  const int nw = gridDim.x*4;
  for (int row = wg; row < N; row += nw){
    float xr = x[(size_t)row*D + lane];
    float aq=bqv, ak=bkv, av=bvv, as_=bsv;
    #pragma unroll
    for (int j=0;j<D;++j){
      float xj = __shfl(xr, j, 64);
      aq  = fmaf(xj, W[0][j*D+lane], aq);
      ak  = fmaf(xj, W[1][j*D+lane], ak);
      av  = fmaf(xj, W[2][j*D+lane], av);
      as_ = fmaf(xj, W[3][j*D+lane], as_);
    }
    size_t o = (size_t)row*D + lane;
    q[o]=aq; k[o]=ak; v[o]=av; agg[o]=as_;
  }
}

// Per-edge attention logits + segment max via encoded atomicMax.
__global__ __launch_bounds__(256) void k_logits(
    const int* __restrict__ esrc, const int* __restrict__ edst,
    const float* __restrict__ q, const float* __restrict__ k,
    float* __restrict__ lg, unsigned* __restrict__ nmax, int E)
{
  int e = blockIdx.x*256 + threadIdx.x;
  if (e >= E) return;
  int s = esrc[e], d = edst[e];
  const float4* qp = (const float4*)(q + (size_t)d*D);
  const float4* kp = (const float4*)(k + (size_t)s*D);
  float acc = 0.f;
  #pragma unroll
  for (int i=0;i<16;++i){
    float4 a = qp[i]; float4 b = kp[i];
    acc += a.x*b.x + a.y*b.y + a.z*b.z + a.w*b.w;
  }
  float l = acc * 0.125f;   // 1/sqrt(64)
  lg[e] = l;
  atomicMax(nmax + d, encf(l));
}

// ex = exp(logit - segmax[dst]) (in-place), denom += ex.
__global__ __launch_bounds__(256) void k_expsum(
    const int* __restrict__ edst, const unsigned* __restrict__ nmax,
    float* __restrict__ lg, float* __restrict__ denom, int E)
{
  int e = blockIdx.x*256 + threadIdx.x;
  if (e >= E) return;
  int d = edst[e];
  float m = decf(nmax[d]);
  float ex = expf(lg[e] - m);
  lg[e] = ex;
  atomicAdd(denom + d, ex);
}

// agg[dst] += alpha * v[src]; 4 threads per edge, 16 dims each.
__global__ __launch_bounds__(256) void k_scatter(
    const int* __restrict__ esrc, const int* __restrict__ edst,
    const float* __restrict__ ex, const float* __restrict__ denom,
    const float* __restrict__ v, float* __restrict__ agg, int E)
{
  int t = blockIdx.x*256 + threadIdx.x;
  int e = t >> 2;
  if (e >= E) return;
  int c = t & 3;
  int s = esrc[e], d = edst[e];
  float alpha = ex[e] / denom[d];
  const float4* vp = (const float4*)(v + (size_t)s*D) + c*4;
  float* ap = agg + (size_t)d*D + c*16;
  #pragma unroll
  for (int i=0;i<4;++i){
    float4 vv = vp[i];
    atomicAdd(ap + i*4 + 0, alpha*vv.x);
    atomicAdd(ap + i*4 + 1, alpha*vv.y);
    atomicAdd(ap + i*4 + 2, alpha*vv.z);
    atomicAdd(ap + i*4 + 3, alpha*vv.w);
  }
}

// ReLU + per-graph mean-pool partial sums. One block per contiguous node
// chunk; batch is sorted so each block touches few graphs.
__global__ __launch_bounds__(256) void k_pool(
    const float* __restrict__ agg, const int* __restrict__ batch,
    float* __restrict__ gsum, float* __restrict__ gcnt, int N, int npb)
{
  __shared__ float ls[NG*D];   // 16 KiB
  __shared__ float lc[NG];
  for (int i = threadIdx.x; i < NG*D; i += 256) ls[i] = 0.f;
  if (threadIdx.x < NG) lc[threadIdx.x] = 0.f;
  __syncthreads();
  const int lane = threadIdx.x & 63;
  const int wid  = threadIdx.x >> 6;
  int start = blockIdx.x * npb;
  int end = min(start + npb, N);
  if (start >= N) return;
  for (int row = start + wid; row < end; row += 4){
    int g = batch[row];
    float val = fmaxf(agg[(size_t)row*D + lane], 0.f);
    atomicAdd(&ls[g*D + lane], val);
    if (lane == 0) atomicAdd(&lc[g], 1.0f);
  }
  __syncthreads();
  int g0 = batch[start], g1 = batch[end-1];
  int nrows = g1 - g0 + 1;
  for (int idx = threadIdx.x; idx < nrows*D; idx += 256){
    int g = g0 + (idx >> 6); int dd = idx & 63;
    float vsum = ls[g*D + dd];
    if (vsum != 0.f) atomicAdd(gsum + g*D + dd, vsum);
  }
  if ((int)threadIdx.x < nrows){
    float c = lc[g0 + threadIdx.x];
    if (c != 0.f) atomicAdd(gcnt + g0 + threadIdx.x, c);
  }
}

__global__ __launch_bounds__(256) void k_final(
    const float* __restrict__ gsum, const float* __restrict__ gcnt,
    float* __restrict__ out, int n)
{
  int i = blockIdx.x*256 + threadIdx.x;
  if (i >= n) return;
  int g = i >> 6;
  out[i] = gsum[i] / fmaxf(gcnt[g], 1.0f);
}

extern "C" void kernel_launch(void* const* d_in, const int* in_sizes, int n_in,
                              void* d_out, int out_size, void* d_ws, size_t ws_size,
                              hipStream_t stream)
{
  const float* x   = (const float*)d_in[0];
  const int*  ei   = (const int*)d_in[1];
  const int*  batch= (const int*)d_in[2];
  const float* Wq  = (const float*)d_in[3];
  const float* bq  = (const float*)d_in[4];
  const float* Wk  = (const float*)d_in[5];
  const float* bk  = (const float*)d_in[6];
  const float* Wv  = (const float*)d_in[7];
  const float* bv  = (const float*)d_in[8];
  const float* Ws  = (const float*)d_in[9];
  const float* bs  = (const float*)d_in[10];
  float* out = (float*)d_out;

  const int N = in_sizes[0] / D;   // 50000
  const int E = in_sizes[1] / 2;   // 800000
  const int* esrc = ei;
  const int* edst = ei + E;

  float* ws = (float*)d_ws;
  size_t off = 0;
  float* q     = ws + off; off += (size_t)N*D;
  float* k     = ws + off; off += (size_t)N*D;
  float* v     = ws + off; off += (size_t)N*D;
  float* agg   = ws + off; off += (size_t)N*D;
  float* lg    = ws + off; off += (size_t)E;      // logits, then ex in-place
  unsigned* nmax = (unsigned*)(ws + off); off += N;
  float* denom = ws + off; off += N;
  float* gsum  = ws + off; off += (size_t)NG*D;
  float* gcnt  = ws + off; off += NG;

  // zero-init [nmax | denom | gsum | gcnt] (contiguous).
  size_t zbytes = ((size_t)N + (size_t)N + (size_t)NG*D + NG) * sizeof(float);
  hipMemsetAsync((void*)nmax, 0, zbytes, stream);

  k_linear4<<<512, 256, 0, stream>>>(x, Wq,bq, Wk,bk, Wv,bv, Ws,bs, q,k,v,agg, N);
  k_logits<<<(E+255)/256, 256, 0, stream>>>(esrc, edst, q, k, lg, nmax, E);
  k_expsum<<<(E+255)/256, 256, 0, stream>>>(edst, nmax, lg, denom, E);
  k_scatter<<<((E*4)+255)/256, 256, 0, stream>>>(esrc, edst, lg, denom, v, agg, E);
  const int npb = 1024;
  k_pool<<<(N+npb-1)/npb, 256, 0, stream>>>(agg, batch, gsum, gcnt, N, npb);
  k_final<<<(NG*D+255)/256, 256, 0, stream>>>(gsum, gcnt, out, NG*D);
}

// Round 3
// 382.599 us; speedup vs baseline: 8.7859x; 8.7859x over previous
//
#include <hip/hip_runtime.h>

#define D 64
#define NG 64

// ---------- pass 1: fused x@{Wq,Wk,Wv,Ws} + bias ----------
__global__ __launch_bounds__(256) void k_linear4(
    const float* __restrict__ x,
    const float* __restrict__ Wq, const float* __restrict__ bq,
    const float* __restrict__ Wk, const float* __restrict__ bk,
    const float* __restrict__ Wv, const float* __restrict__ bv,
    const float* __restrict__ Ws, const float* __restrict__ bs,
    float* __restrict__ q, float* __restrict__ k, float* __restrict__ v,
    float* __restrict__ sp, int N)
{
  __shared__ float W[4][D*D];   // 64 KiB
  for (int i = threadIdx.x; i < D*D; i += 256){
    W[0][i]=Wq[i]; W[1][i]=Wk[i]; W[2][i]=Wv[i]; W[3][i]=Ws[i];
  }
  __syncthreads();
  const int lane = threadIdx.x & 63;
  const int wid  = threadIdx.x >> 6;
  const float bqv=bq[lane], bkv=bk[lane], bvv=bv[lane], bsv=bs[lane];
  const int wg = blockIdx.x*4 + wid;
  const int nw = gridDim.x*4;
  for (int row = wg; row < N; row += nw){
    float xr = x[(size_t)row*D + lane];
    float aq=bqv, ak=bkv, av=bvv, as_=bsv;
    #pragma unroll
    for (int j=0;j<D;++j){
      float xj = __shfl(xr, j, 64);
      aq  = fmaf(xj, W[0][j*D+lane], aq);
      ak  = fmaf(xj, W[1][j*D+lane], ak);
      av  = fmaf(xj, W[2][j*D+lane], av);
      as_ = fmaf(xj, W[3][j*D+lane], as_);
    }
    size_t o = (size_t)row*D + lane;
    q[o]=aq; k[o]=ak; v[o]=av; sp[o]=as_;
  }
}

// ---------- CSR build (group edges by dst) ----------
__global__ __launch_bounds__(256) void k_hist(
    const int* __restrict__ edst, int* __restrict__ deg, int E)
{
  int e = blockIdx.x*256 + threadIdx.x;
  if (e < E) atomicAdd(deg + edst[e], 1);
}

__global__ __launch_bounds__(256) void k_scan1(
    const int* __restrict__ deg, int* __restrict__ ptr, int* __restrict__ bsum, int N)
{
  __shared__ int s[256];
  int t = threadIdx.x;
  int i = blockIdx.x*256 + t;
  int val = (i < N) ? deg[i] : 0;
  s[t] = val; __syncthreads();
  #pragma unroll
  for (int off=1; off<256; off<<=1){
    int tmp = (t>=off) ? s[t-off] : 0;
    __syncthreads();
    s[t] += tmp;
    __syncthreads();
  }
  if (i < N) ptr[i] = s[t] - val;          // exclusive
  if (t == 255) bsum[blockIdx.x] = s[255]; // block total
}

__global__ __launch_bounds__(256) void k_scan2(
    const int* __restrict__ bsum, int* __restrict__ boff, int NB)
{
  __shared__ int s[256];
  int t = threadIdx.x;
  int val = (t < NB) ? bsum[t] : 0;
  s[t] = val; __syncthreads();
  #pragma unroll
  for (int off=1; off<256; off<<=1){
    int tmp = (t>=off) ? s[t-off] : 0;
    __syncthreads();
    s[t] += tmp;
    __syncthreads();
  }
  if (t < NB) boff[t] = s[t] - val;
}

__global__ __launch_bounds__(256) void k_scan3(
    int* __restrict__ ptr, const int* __restrict__ boff,
    int* __restrict__ cursor, int N)
{
  int i = blockIdx.x*256 + threadIdx.x;
  if (i < N){
    int p = ptr[i] + boff[blockIdx.x];
    ptr[i] = p;
    cursor[i] = p;
  }
}

__global__ __launch_bounds__(256) void k_fill(
    const int* __restrict__ esrc, const int* __restrict__ edst,
    int* __restrict__ cursor, int* __restrict__ csr_src, int E)
{
  int e = blockIdx.x*256 + threadIdx.x;
  if (e >= E) return;
  int pos = atomicAdd(cursor + edst[e], 1);
  csr_src[pos] = esrc[e];
}

// ---------- fused attention gather: logits + online softmax + PV + skip + ReLU ----------
// One wave per dst node; 4 groups of 16 lanes. ALL cross-lane shuffles execute
// wave-uniformly: uniform trip count T, clamped shuffle source, accumulation
// predicated on the group-uniform (ei < nb).
__global__ __launch_bounds__(256) void k_attend(
    const float* __restrict__ q, const float* __restrict__ k,
    const float* __restrict__ v, float* __restrict__ sp,
    const int* __restrict__ ptr, const int* __restrict__ deg,
    const int* __restrict__ csr_src, int N)
{
  int node = blockIdx.x*4 + (threadIdx.x >> 6);
  if (node >= N) return;
  const int lane = threadIdx.x & 63;
  const int grp  = lane >> 4;
  const int gl   = lane & 15;

  float4 q4 = ((const float4*)(q + (size_t)node*D))[gl];
  int p0 = ptr[node], dg = deg[node];

  float m = -INFINITY, den = 0.f;
  float ax=0.f, ay=0.f, az=0.f, aw=0.f;

  for (int base = 0; base < dg; base += 64){
    int nb = min(64, dg - base);
    int sidx = (lane < nb) ? csr_src[p0 + base + lane] : 0;
    int T = (nb + 3) >> 2;               // uniform trip count for all groups
    for (int t = 0; t < T; ++t){
      int ei  = grp + 4*t;
      int eis = min(ei, nb - 1);         // clamped: always a valid source lane
      int s = __shfl(sidx, eis, 64);     // executed by all 64 lanes
      if (ei < nb){                      // group-uniform predicate
        float4 k4 = ((const float4*)(k + (size_t)s*D))[gl];
        float p = q4.x*k4.x + q4.y*k4.y + q4.z*k4.z + q4.w*k4.w;
        p += __shfl_xor(p, 1, 64);       // within-group; all 16 lanes share pred
        p += __shfl_xor(p, 2, 64);
        p += __shfl_xor(p, 4, 64);
        p += __shfl_xor(p, 8, 64);
        float logit = p * 0.125f;        // 1/sqrt(64)
        float4 v4 = ((const float4*)(v + (size_t)s*D))[gl];
        if (logit > m){
          float sc = expf(m - logit);    // exp(-inf)=0 on first edge
          den *= sc; ax *= sc; ay *= sc; az *= sc; aw *= sc;
          m = logit;
        }
        float ex = expf(logit - m);
        den += ex;
        ax = fmaf(ex, v4.x, ax);
        ay = fmaf(ex, v4.y, ay);
        az = fmaf(ex, v4.z, az);
        aw = fmaf(ex, v4.w, aw);
      }
    }
  }

  // merge the 4 groups (lanes gl, gl+16, gl+32, gl+48) — wave-uniform
  #pragma unroll
  for (int off = 16; off <= 32; off <<= 1){
    float m2   = __shfl_xor(m,   off, 64);
    float den2 = __shfl_xor(den, off, 64);
    float bx = __shfl_xor(ax, off, 64);
    float by = __shfl_xor(ay, off, 64);
    float bz = __shfl_xor(az, off, 64);
    float bw = __shfl_xor(aw, off, 64);
    float M = fmaxf(m, m2);
    float s1 = (m  > -INFINITY) ? expf(m  - M) : 0.f;
    float s2 = (m2 > -INFINITY) ? expf(m2 - M) : 0.f;
    den = den*s1 + den2*s2;
    ax = ax*s1 + bx*s2;
    ay = ay*s1 + by*s2;
    az = az*s1 + bz*s2;
    aw = aw*s1 + bw*s2;
    m = M;
  }

  if (grp == 0){
    float4 s4 = ((const float4*)(sp + (size_t)node*D))[gl];
    float4 o;
    if (dg > 0){
      float inv = 1.f/den;
      o.x = fmaf(ax, inv, s4.x);
      o.y = fmaf(ay, inv, s4.y);
      o.z = fmaf(az, inv, s4.z);
      o.w = fmaf(aw, inv, s4.w);
    } else {
      o = s4;
    }
    o.x = fmaxf(o.x, 0.f); o.y = fmaxf(o.y, 0.f);
    o.z = fmaxf(o.z, 0.f); o.w = fmaxf(o.w, 0.f);
    ((float4*)(sp + (size_t)node*D))[gl] = o;
  }
}

// ---------- mean pool ----------
__global__ __launch_bounds__(256) void k_pool(
    const float* __restrict__ out_rows, const int* __restrict__ batch,
    float* __restrict__ gsum, float* __restrict__ gcnt, int N, int npb)
{
  __shared__ float ls[NG*D];
  __shared__ float lc[NG];
  for (int i = threadIdx.x; i < NG*D; i += 256) ls[i] = 0.f;
  if (threadIdx.x < NG) lc[threadIdx.x] = 0.f;
  __syncthreads();
  const int lane = threadIdx.x & 63;
  const int wid  = threadIdx.x >> 6;
  int start = blockIdx.x * npb;
  int end = min(start + npb, N);
  if (start >= N) return;
  for (int row = start + wid; row < end; row += 4){
    int g = batch[row];
    float val = out_rows[(size_t)row*D + lane];
    atomicAdd(&ls[g*D + lane], val);
    if (lane == 0) atomicAdd(&lc[g], 1.0f);
  }
  __syncthreads();
  int g0 = batch[start], g1 = batch[end-1];
  int nrows = g1 - g0 + 1;
  for (int idx = threadIdx.x; idx < nrows*D; idx += 256){
    int g = g0 + (idx >> 6); int dd = idx & 63;
    float vsum = ls[g*D + dd];
    if (vsum != 0.f) atomicAdd(gsum + g*D + dd, vsum);
  }
  if ((int)threadIdx.x < nrows){
    float c = lc[g0 + threadIdx.x];
    if (c != 0.f) atomicAdd(gcnt + g0 + threadIdx.x, c);
  }
}

__global__ __launch_bounds__(256) void k_final(
    const float* __restrict__ gsum, const float* __restrict__ gcnt,
    float* __restrict__ out, int n)
{
  int i = blockIdx.x*256 + threadIdx.x;
  if (i >= n) return;
  int g = i >> 6;
  out[i] = gsum[i] / fmaxf(gcnt[g], 1.0f);
}

extern "C" void kernel_launch(void* const* d_in, const int* in_sizes, int n_in,
                              void* d_out, int out_size, void* d_ws, size_t ws_size,
                              hipStream_t stream)
{
  const float* x   = (const float*)d_in[0];
  const int*  ei   = (const int*)d_in[1];
  const int*  batch= (const int*)d_in[2];
  const float* Wq  = (const float*)d_in[3];
  const float* bq  = (const float*)d_in[4];
  const float* Wk  = (const float*)d_in[5];
  const float* bk  = (const float*)d_in[6];
  const float* Wv  = (const float*)d_in[7];
  const float* bv  = (const float*)d_in[8];
  const float* Ws  = (const float*)d_in[9];
  const float* bs  = (const float*)d_in[10];
  float* out = (float*)d_out;

  const int N = in_sizes[0] / D;   // 50000
  const int E = in_sizes[1] / 2;   // 800000
  const int* esrc = ei;
  const int* edst = ei + E;

  float* ws = (float*)d_ws;
  size_t off = 0;
  float* q    = ws + off; off += (size_t)N*D;
  float* k    = ws + off; off += (size_t)N*D;
  float* v    = ws + off; off += (size_t)N*D;
  float* sp   = ws + off; off += (size_t)N*D;   // s-proj in, relu(out) in-place
  // zero region: [deg | gsum | gcnt]
  int*   deg  = (int*)(ws + off);  off += N;
  float* gsum = ws + off; off += (size_t)NG*D;
  float* gcnt = ws + off; off += NG;
  int*   ptr  = (int*)(ws + off);  off += N;
  int*   cursor = (int*)(ws + off); off += N;
  int*   bsum = (int*)(ws + off);  off += 256;
  int*   boff = (int*)(ws + off);  off += 256;
  int*   csr_src = (int*)(ws + off); off += E;

  size_t zbytes = ((size_t)N + (size_t)NG*D + NG) * sizeof(float);
  hipMemsetAsync((void*)deg, 0, zbytes, stream);

  const int NB = (N + 255) / 256;

  k_linear4<<<512, 256, 0, stream>>>(x, Wq,bq, Wk,bk, Wv,bv, Ws,bs, q,k,v,sp, N);
  k_hist <<<(E+255)/256, 256, 0, stream>>>(edst, deg, E);
  k_scan1<<<NB, 256, 0, stream>>>(deg, ptr, bsum, N);
  k_scan2<<<1, 256, 0, stream>>>(bsum, boff, NB);
  k_scan3<<<NB, 256, 0, stream>>>(ptr, boff, cursor, N);
  k_fill <<<(E+255)/256, 256, 0, stream>>>(esrc, edst, cursor, csr_src, E);
  k_attend<<<(N+3)/4, 256, 0, stream>>>(q, k, v, sp, ptr, deg, csr_src, N);
  const int npb = 1024;
  k_pool<<<(N+npb-1)/npb, 256, 0, stream>>>(sp, batch, gsum, gcnt, N, npb);
  k_final<<<(NG*D+255)/256, 256, 0, stream>>>(gsum, gcnt, out, NG*D);
}

// Round 4
// 289.235 us; speedup vs baseline: 11.6219x; 1.3228x over previous
//
#include <hip/hip_runtime.h>

#define D 64
#define NG 64

typedef float f32x16 __attribute__((ext_vector_type(16)));

// ---------- pass 1: fused x@{Wq,Wk,Wv,Ws} + bias ----------
// Wave w of each block computes matrix w. Lane l holds W-column l in 64 VGPRs.
// The (wave-uniform) x row is broadcast through SGPRs via s_load_dwordx16, so
// the inner loop is pure v_fma_f32 with an SGPR multiplier — no LDS, no shfl.
__global__ __launch_bounds__(256) void k_linear4(
    const float* __restrict__ x,
    const float* __restrict__ Wq, const float* __restrict__ bq,
    const float* __restrict__ Wk, const float* __restrict__ bk,
    const float* __restrict__ Wv, const float* __restrict__ bv,
    const float* __restrict__ Ws, const float* __restrict__ bs,
    float* __restrict__ q, float* __restrict__ k, float* __restrict__ v,
    float* __restrict__ sp, int N)
{
  const int lane = threadIdx.x & 63;
  const int w    = threadIdx.x >> 6;   // wave id = matrix id

  const float* Wm = (w==0) ? Wq : (w==1) ? Wk : (w==2) ? Wv : Ws;
  const float* bm = (w==0) ? bq : (w==1) ? bk : (w==2) ? bv : bs;
  float*       dm = (w==0) ? q  : (w==1) ? k  : (w==2) ? v  : sp;

  // column `lane` of Wm into registers (coalesced row-wise loads)
  float wr[D];
  #pragma unroll
  for (int j = 0; j < D; ++j) wr[j] = Wm[j*D + lane];
  const float bias = bm[lane];

  for (int row = blockIdx.x; row < N; row += gridDim.x){
    const float* xrow = x + (size_t)row * D;
    f32x16 x0, x1, x2, x3;
    asm volatile("s_load_dwordx16 %0, %1, 0x0"  : "=s"(x0) : "s"(xrow));
    asm volatile("s_load_dwordx16 %0, %1, 0x40" : "=s"(x1) : "s"(xrow));
    asm volatile("s_load_dwordx16 %0, %1, 0x80" : "=s"(x2) : "s"(xrow));
    asm volatile("s_load_dwordx16 %0, %1, 0xc0" : "=s"(x3) : "s"(xrow));
    // "+s" ties force every consumer of x0..x3 to sit after this waitcnt.
    asm volatile("s_waitcnt lgkmcnt(0)"
                 : "+s"(x0), "+s"(x1), "+s"(x2), "+s"(x3));
    float acc = bias;
    #pragma unroll
    for (int j = 0; j < 16; ++j) acc = fmaf(x0[j], wr[j],      acc);
    #pragma unroll
    for (int j = 0; j < 16; ++j) acc = fmaf(x1[j], wr[16 + j], acc);
    #pragma unroll
    for (int j = 0; j < 16; ++j) acc = fmaf(x2[j], wr[32 + j], acc);
    #pragma unroll
    for (int j = 0; j < 16; ++j) acc = fmaf(x3[j], wr[48 + j], acc);
    dm[(size_t)row * D + lane] = acc;
  }
}

// ---------- CSR build (group edges by dst) ----------
__global__ __launch_bounds__(256) void k_hist(
    const int* __restrict__ edst, int* __restrict__ deg, int E)
{
  int e = blockIdx.x*256 + threadIdx.x;
  if (e < E) atomicAdd(deg + edst[e], 1);
}

__global__ __launch_bounds__(256) void k_scan1(
    const int* __restrict__ deg, int* __restrict__ ptr, int* __restrict__ bsum, int N)
{
  __shared__ int s[256];
  int t = threadIdx.x;
  int i = blockIdx.x*256 + t;
  int val = (i < N) ? deg[i] : 0;
  s[t] = val; __syncthreads();
  #pragma unroll
  for (int off=1; off<256; off<<=1){
    int tmp = (t>=off) ? s[t-off] : 0;
    __syncthreads();
    s[t] += tmp;
    __syncthreads();
  }
  if (i < N) ptr[i] = s[t] - val;          // exclusive
  if (t == 255) bsum[blockIdx.x] = s[255]; // block total
}

__global__ __launch_bounds__(256) void k_scan2(
    const int* __restrict__ bsum, int* __restrict__ boff, int NB)
{
  __shared__ int s[256];
  int t = threadIdx.x;
  int val = (t < NB) ? bsum[t] : 0;
  s[t] = val; __syncthreads();
  #pragma unroll
  for (int off=1; off<256; off<<=1){
    int tmp = (t>=off) ? s[t-off] : 0;
    __syncthreads();
    s[t] += tmp;
    __syncthreads();
  }
  if (t < NB) boff[t] = s[t] - val;
}

__global__ __launch_bounds__(256) void k_scan3(
    int* __restrict__ ptr, const int* __restrict__ boff,
    int* __restrict__ cursor, int N)
{
  int i = blockIdx.x*256 + threadIdx.x;
  if (i < N){
    int p = ptr[i] + boff[blockIdx.x];
    ptr[i] = p;
    cursor[i] = p;
  }
}

__global__ __launch_bounds__(256) void k_fill(
    const int* __restrict__ esrc, const int* __restrict__ edst,
    int* __restrict__ cursor, int* __restrict__ csr_src, int E)
{
  int e = blockIdx.x*256 + threadIdx.x;
  if (e >= E) return;
  int pos = atomicAdd(cursor + edst[e], 1);
  csr_src[pos] = esrc[e];
}

// ---------- fused attention gather: logits + online softmax + PV + skip + ReLU ----------
__global__ __launch_bounds__(256) void k_attend(
    const float* __restrict__ q, const float* __restrict__ k,
    const float* __restrict__ v, float* __restrict__ sp,
    const int* __restrict__ ptr, const int* __restrict__ deg,
    const int* __restrict__ csr_src, int N)
{
  int node = blockIdx.x*4 + (threadIdx.x >> 6);
  if (node >= N) return;
  const int lane = threadIdx.x & 63;
  const int grp  = lane >> 4;
  const int gl   = lane & 15;

  float4 q4 = ((const float4*)(q + (size_t)node*D))[gl];
  int p0 = ptr[node], dg = deg[node];

  float m = -INFINITY, den = 0.f;
  float ax=0.f, ay=0.f, az=0.f, aw=0.f;

  for (int base = 0; base < dg; base += 64){
    int nb = min(64, dg - base);
    int sidx = (lane < nb) ? csr_src[p0 + base + lane] : 0;
    int T = (nb + 3) >> 2;               // uniform trip count for all groups
    for (int t = 0; t < T; ++t){
      int ei  = grp + 4*t;
      int eis = min(ei, nb - 1);         // clamped: always a valid source lane
      int s = __shfl(sidx, eis, 64);     // executed by all 64 lanes
      if (ei < nb){                      // group-uniform predicate
        float4 k4 = ((const float4*)(k + (size_t)s*D))[gl];
        float p = q4.x*k4.x + q4.y*k4.y + q4.z*k4.z + q4.w*k4.w;
        p += __shfl_xor(p, 1, 64);
        p += __shfl_xor(p, 2, 64);
        p += __shfl_xor(p, 4, 64);
        p += __shfl_xor(p, 8, 64);
        float logit = p * 0.125f;        // 1/sqrt(64)
        float4 v4 = ((const float4*)(v + (size_t)s*D))[gl];
        if (logit > m){
          float sc = expf(m - logit);    // exp(-inf)=0 on first edge
          den *= sc; ax *= sc; ay *= sc; az *= sc; aw *= sc;
          m = logit;
        }
        float ex = expf(logit - m);
        den += ex;
        ax = fmaf(ex, v4.x, ax);
        ay = fmaf(ex, v4.y, ay);
        az = fmaf(ex, v4.z, az);
        aw = fmaf(ex, v4.w, aw);
      }
    }
  }

  // merge the 4 groups (lanes gl, gl+16, gl+32, gl+48) — wave-uniform
  #pragma unroll
  for (int off = 16; off <= 32; off <<= 1){
    float m2   = __shfl_xor(m,   off, 64);
    float den2 = __shfl_xor(den, off, 64);
    float bx = __shfl_xor(ax, off, 64);
    float by = __shfl_xor(ay, off, 64);
    float bz = __shfl_xor(az, off, 64);
    float bw = __shfl_xor(aw, off, 64);
    float M = fmaxf(m, m2);
    float s1 = (m  > -INFINITY) ? expf(m  - M) : 0.f;
    float s2 = (m2 > -INFINITY) ? expf(m2 - M) : 0.f;
    den = den*s1 + den2*s2;
    ax = ax*s1 + bx*s2;
    ay = ay*s1 + by*s2;
    az = az*s1 + bz*s2;
    aw = aw*s1 + bw*s2;
    m = M;
  }

  if (grp == 0){
    float4 s4 = ((const float4*)(sp + (size_t)node*D))[gl];
    float4 o;
    if (dg > 0){
      float inv = 1.f/den;
      o.x = fmaf(ax, inv, s4.x);
      o.y = fmaf(ay, inv, s4.y);
      o.z = fmaf(az, inv, s4.z);
      o.w = fmaf(aw, inv, s4.w);
    } else {
      o = s4;
    }
    o.x = fmaxf(o.x, 0.f); o.y = fmaxf(o.y, 0.f);
    o.z = fmaxf(o.z, 0.f); o.w = fmaxf(o.w, 0.f);
    ((float4*)(sp + (size_t)node*D))[gl] = o;
  }
}

// ---------- mean pool ----------
__global__ __launch_bounds__(256) void k_pool(
    const float* __restrict__ out_rows, const int* __restrict__ batch,
    float* __restrict__ gsum, float* __restrict__ gcnt, int N, int npb)
{
  __shared__ float ls[NG*D];
  __shared__ float lc[NG];
  for (int i = threadIdx.x; i < NG*D; i += 256) ls[i] = 0.f;
  if (threadIdx.x < NG) lc[threadIdx.x] = 0.f;
  __syncthreads();
  const int lane = threadIdx.x & 63;
  const int wid  = threadIdx.x >> 6;
  int start = blockIdx.x * npb;
  int end = min(start + npb, N);
  if (start >= N) return;
  for (int row = start + wid; row < end; row += 4){
    int g = batch[row];
    float val = out_rows[(size_t)row*D + lane];
    atomicAdd(&ls[g*D + lane], val);
    if (lane == 0) atomicAdd(&lc[g], 1.0f);
  }
  __syncthreads();
  int g0 = batch[start], g1 = batch[end-1];
  int nrows = g1 - g0 + 1;
  for (int idx = threadIdx.x; idx < nrows*D; idx += 256){
    int g = g0 + (idx >> 6); int dd = idx & 63;
    float vsum = ls[g*D + dd];
    if (vsum != 0.f) atomicAdd(gsum + g*D + dd, vsum);
  }
  if ((int)threadIdx.x < nrows){
    float c = lc[g0 + threadIdx.x];
    if (c != 0.f) atomicAdd(gcnt + g0 + threadIdx.x, c);
  }
}

__global__ __launch_bounds__(256) void k_final(
    const float* __restrict__ gsum, const float* __restrict__ gcnt,
    float* __restrict__ out, int n)
{
  int i = blockIdx.x*256 + threadIdx.x;
  if (i >= n) return;
  int g = i >> 6;
  out[i] = gsum[i] / fmaxf(gcnt[g], 1.0f);
}

extern "C" void kernel_launch(void* const* d_in, const int* in_sizes, int n_in,
                              void* d_out, int out_size, void* d_ws, size_t ws_size,
                              hipStream_t stream)
{
  const float* x   = (const float*)d_in[0];
  const int*  ei   = (const int*)d_in[1];
  const int*  batch= (const int*)d_in[2];
  const float* Wq  = (const float*)d_in[3];
  const float* bq  = (const float*)d_in[4];
  const float* Wk  = (const float*)d_in[5];
  const float* bk  = (const float*)d_in[6];
  const float* Wv  = (const float*)d_in[7];
  const float* bv  = (const float*)d_in[8];
  const float* Ws  = (const float*)d_in[9];
  const float* bs  = (const float*)d_in[10];
  float* out = (float*)d_out;

  const int N = in_sizes[0] / D;   // 50000
  const int E = in_sizes[1] / 2;   // 800000
  const int* esrc = ei;
  const int* edst = ei + E;

  float* ws = (float*)d_ws;
  size_t off = 0;
  float* q    = ws + off; off += (size_t)N*D;
  float* k    = ws + off; off += (size_t)N*D;
  float* v    = ws + off; off += (size_t)N*D;
  float* sp   = ws + off; off += (size_t)N*D;   // s-proj in, relu(out) in-place
  // zero region: [deg | gsum | gcnt]
  int*   deg  = (int*)(ws + off);  off += N;
  float* gsum = ws + off; off += (size_t)NG*D;
  float* gcnt = ws + off; off += NG;
  int*   ptr  = (int*)(ws + off);  off += N;
  int*   cursor = (int*)(ws + off); off += N;
  int*   bsum = (int*)(ws + off);  off += 256;
  int*   boff = (int*)(ws + off);  off += 256;
  int*   csr_src = (int*)(ws + off); off += E;

  size_t zbytes = ((size_t)N + (size_t)NG*D + NG) * sizeof(float);
  hipMemsetAsync((void*)deg, 0, zbytes, stream);

  const int NB = (N + 255) / 256;

  k_linear4<<<1024, 256, 0, stream>>>(x, Wq,bq, Wk,bk, Wv,bv, Ws,bs, q,k,v,sp, N);
  k_hist <<<(E+255)/256, 256, 0, stream>>>(edst, deg, E);
  k_scan1<<<NB, 256, 0, stream>>>(deg, ptr, bsum, N);
  k_scan2<<<1, 256, 0, stream>>>(bsum, boff, NB);
  k_scan3<<<NB, 256, 0, stream>>>(ptr, boff, cursor, N);
  k_fill <<<(E+255)/256, 256, 0, stream>>>(esrc, edst, cursor, csr_src, E);
  k_attend<<<(N+3)/4, 256, 0, stream>>>(q, k, v, sp, ptr, deg, csr_src, N);
  const int npb = 1024;
  k_pool<<<(N+npb-1)/npb, 256, 0, stream>>>(sp, batch, gsum, gcnt, N, npb);
  k_final<<<(NG*D+255)/256, 256, 0, stream>>>(gsum, gcnt, out, NG*D);
}

// Round 5
// 219.840 us; speedup vs baseline: 15.2904x; 1.3157x over previous
//
#include <hip/hip_runtime.h>

#define D 64
#define NG 64

typedef float f32x16 __attribute__((ext_vector_type(16)));

// ---------- pass 1: fused x@{Wq,Wk,Wv,Ws} + bias ----------
// Wave w of each block computes matrix w. Lane l holds W-column l in 64 VGPRs.
// The (wave-uniform) x row is broadcast through SGPRs via s_load_dwordx16, so
// the inner loop is pure v_fma_f32 with an SGPR multiplier — no LDS, no shfl.
__global__ __launch_bounds__(256) void k_linear4(
    const float* __restrict__ x,
    const float* __restrict__ Wq, const float* __restrict__ bq,
    const float* __restrict__ Wk, const float* __restrict__ bk,
    const float* __restrict__ Wv, const float* __restrict__ bv,
    const float* __restrict__ Ws, const float* __restrict__ bs,
    float* __restrict__ q, float* __restrict__ k, float* __restrict__ v,
    float* __restrict__ sp, int N)
{
  const int lane = threadIdx.x & 63;
  const int w    = threadIdx.x >> 6;   // wave id = matrix id

  const float* Wm = (w==0) ? Wq : (w==1) ? Wk : (w==2) ? Wv : Ws;
  const float* bm = (w==0) ? bq : (w==1) ? bk : (w==2) ? bv : bs;
  float*       dm = (w==0) ? q  : (w==1) ? k  : (w==2) ? v  : sp;

  float wr[D];
  #pragma unroll
  for (int j = 0; j < D; ++j) wr[j] = Wm[j*D + lane];
  const float bias = bm[lane];

  for (int row = blockIdx.x; row < N; row += gridDim.x){
    const float* xrow = x + (size_t)row * D;
    f32x16 x0, x1, x2, x3;
    asm volatile("s_load_dwordx16 %0, %1, 0x0"  : "=s"(x0) : "s"(xrow));
    asm volatile("s_load_dwordx16 %0, %1, 0x40" : "=s"(x1) : "s"(xrow));
    asm volatile("s_load_dwordx16 %0, %1, 0x80" : "=s"(x2) : "s"(xrow));
    asm volatile("s_load_dwordx16 %0, %1, 0xc0" : "=s"(x3) : "s"(xrow));
    asm volatile("s_waitcnt lgkmcnt(0)"
                 : "+s"(x0), "+s"(x1), "+s"(x2), "+s"(x3));
    float acc = bias;
    #pragma unroll
    for (int j = 0; j < 16; ++j) acc = fmaf(x0[j], wr[j],      acc);
    #pragma unroll
    for (int j = 0; j < 16; ++j) acc = fmaf(x1[j], wr[16 + j], acc);
    #pragma unroll
    for (int j = 0; j < 16; ++j) acc = fmaf(x2[j], wr[32 + j], acc);
    #pragma unroll
    for (int j = 0; j < 16; ++j) acc = fmaf(x3[j], wr[48 + j], acc);
    dm[(size_t)row * D + lane] = acc;
  }
}

// ---------- CSR build (group edges by dst) ----------
__global__ __launch_bounds__(256) void k_hist(
    const int* __restrict__ edst, int* __restrict__ deg, int E)
{
  int e = blockIdx.x*256 + threadIdx.x;
  if (e < E) atomicAdd(deg + edst[e], 1);
}

__global__ __launch_bounds__(256) void k_scan1(
    const int* __restrict__ deg, int* __restrict__ ptr, int* __restrict__ bsum, int N)
{
  __shared__ int s[256];
  int t = threadIdx.x;
  int i = blockIdx.x*256 + t;
  int val = (i < N) ? deg[i] : 0;
  s[t] = val; __syncthreads();
  #pragma unroll
  for (int off=1; off<256; off<<=1){
    int tmp = (t>=off) ? s[t-off] : 0;
    __syncthreads();
    s[t] += tmp;
    __syncthreads();
  }
  if (i < N) ptr[i] = s[t] - val;          // exclusive
  if (t == 255) bsum[blockIdx.x] = s[255]; // block total
}

__global__ __launch_bounds__(256) void k_scan2(
    const int* __restrict__ bsum, int* __restrict__ boff, int NB)
{
  __shared__ int s[256];
  int t = threadIdx.x;
  int val = (t < NB) ? bsum[t] : 0;
  s[t] = val; __syncthreads();
  #pragma unroll
  for (int off=1; off<256; off<<=1){
    int tmp = (t>=off) ? s[t-off] : 0;
    __syncthreads();
    s[t] += tmp;
    __syncthreads();
  }
  if (t < NB) boff[t] = s[t] - val;
}

__global__ __launch_bounds__(256) void k_scan3(
    int* __restrict__ ptr, const int* __restrict__ boff,
    int* __restrict__ cursor, int N)
{
  int i = blockIdx.x*256 + threadIdx.x;
  if (i < N){
    int p = ptr[i] + boff[blockIdx.x];
    ptr[i] = p;
    cursor[i] = p;
  }
}

__global__ __launch_bounds__(256) void k_fill(
    const int* __restrict__ esrc, const int* __restrict__ edst,
    int* __restrict__ cursor, int* __restrict__ csr_src, int E)
{
  int e = blockIdx.x*256 + threadIdx.x;
  if (e >= E) return;
  int pos = atomicAdd(cursor + edst[e], 1);
  csr_src[pos] = esrc[e];
}

// ---------- fused attention gather: logits + online softmax + PV + skip + ReLU ----------
__global__ __launch_bounds__(256) void k_attend(
    const float* __restrict__ q, const float* __restrict__ k,
    const float* __restrict__ v, float* __restrict__ sp,
    const int* __restrict__ ptr, const int* __restrict__ deg,
    const int* __restrict__ csr_src, int N)
{
  int node = blockIdx.x*4 + (threadIdx.x >> 6);
  if (node >= N) return;
  const int lane = threadIdx.x & 63;
  const int grp  = lane >> 4;
  const int gl   = lane & 15;

  float4 q4 = ((const float4*)(q + (size_t)node*D))[gl];
  int p0 = ptr[node], dg = deg[node];

  float m = -INFINITY, den = 0.f;
  float ax=0.f, ay=0.f, az=0.f, aw=0.f;

  for (int base = 0; base < dg; base += 64){
    int nb = min(64, dg - base);
    int sidx = (lane < nb) ? csr_src[p0 + base + lane] : 0;
    int T = (nb + 3) >> 2;               // uniform trip count for all groups
    for (int t = 0; t < T; ++t){
      int ei  = grp + 4*t;
      int eis = min(ei, nb - 1);         // clamped: always a valid source lane
      int s = __shfl(sidx, eis, 64);     // executed by all 64 lanes
      if (ei < nb){                      // group-uniform predicate
        float4 k4 = ((const float4*)(k + (size_t)s*D))[gl];
        float p = q4.x*k4.x + q4.y*k4.y + q4.z*k4.z + q4.w*k4.w;
        p += __shfl_xor(p, 1, 64);
        p += __shfl_xor(p, 2, 64);
        p += __shfl_xor(p, 4, 64);
        p += __shfl_xor(p, 8, 64);
        float logit = p * 0.125f;        // 1/sqrt(64)
        float4 v4 = ((const float4*)(v + (size_t)s*D))[gl];
        if (logit > m){
          float sc = expf(m - logit);    // exp(-inf)=0 on first edge
          den *= sc; ax *= sc; ay *= sc; az *= sc; aw *= sc;
          m = logit;
        }
        float ex = expf(logit - m);
        den += ex;
        ax = fmaf(ex, v4.x, ax);
        ay = fmaf(ex, v4.y, ay);
        az = fmaf(ex, v4.z, az);
        aw = fmaf(ex, v4.w, aw);
      }
    }
  }

  // merge the 4 groups (lanes gl, gl+16, gl+32, gl+48) — wave-uniform
  #pragma unroll
  for (int off = 16; off <= 32; off <<= 1){
    float m2   = __shfl_xor(m,   off, 64);
    float den2 = __shfl_xor(den, off, 64);
    float bx = __shfl_xor(ax, off, 64);
    float by = __shfl_xor(ay, off, 64);
    float bz = __shfl_xor(az, off, 64);
    float bw = __shfl_xor(aw, off, 64);
    float M = fmaxf(m, m2);
    float s1 = (m  > -INFINITY) ? expf(m  - M) : 0.f;
    float s2 = (m2 > -INFINITY) ? expf(m2 - M) : 0.f;
    den = den*s1 + den2*s2;
    ax = ax*s1 + bx*s2;
    ay = ay*s1 + by*s2;
    az = az*s1 + bz*s2;
    aw = aw*s1 + bw*s2;
    m = M;
  }

  if (grp == 0){
    float4 s4 = ((const float4*)(sp + (size_t)node*D))[gl];
    float4 o;
    if (dg > 0){
      float inv = 1.f/den;
      o.x = fmaf(ax, inv, s4.x);
      o.y = fmaf(ay, inv, s4.y);
      o.z = fmaf(az, inv, s4.z);
      o.w = fmaf(aw, inv, s4.w);
    } else {
      o = s4;
    }
    o.x = fmaxf(o.x, 0.f); o.y = fmaxf(o.y, 0.f);
    o.z = fmaxf(o.z, 0.f); o.w = fmaxf(o.w, 0.f);
    ((float4*)(sp + (size_t)node*D))[gl] = o;
  }
}

// ---------- mean pool: register accumulation per wave strip ----------
// batch is sorted. One wave per 32 contiguous rows; lane l accumulates dim l
// of the current graph run in a register, flushing to global atomics only at
// graph boundaries (63 total) and strip ends. No LDS.
__global__ __launch_bounds__(256) void k_pool(
    const float* __restrict__ rows, const int* __restrict__ batch,
    float* __restrict__ gsum, float* __restrict__ gcnt, int N, int rpw)
{
  const int lane = threadIdx.x & 63;
  const int wid  = threadIdx.x >> 6;
  int wi = blockIdx.x*4 + wid;
  int start = wi * rpw;
  if (start >= N) return;
  int end = min(start + rpw, N);

  float acc = 0.f, cnt = 0.f;
  int gcur = batch[start];
  #pragma unroll 4
  for (int row = start; row < end; ++row){
    int g = batch[row];                     // wave-uniform scalar load
    float val = rows[(size_t)row*D + lane]; // coalesced 256B per wave
    if (g != gcur){
      atomicAdd(gsum + (size_t)gcur*D + lane, acc);
      if (lane == 0) atomicAdd(gcnt + gcur, cnt);
      acc = 0.f; cnt = 0.f; gcur = g;
    }
    acc += val;
    cnt += 1.f;
  }
  atomicAdd(gsum + (size_t)gcur*D + lane, acc);
  if (lane == 0) atomicAdd(gcnt + gcur, cnt);
}

__global__ __launch_bounds__(256) void k_final(
    const float* __restrict__ gsum, const float* __restrict__ gcnt,
    float* __restrict__ out, int n)
{
  int i = blockIdx.x*256 + threadIdx.x;
  if (i >= n) return;
  int g = i >> 6;
  out[i] = gsum[i] / fmaxf(gcnt[g], 1.0f);
}

extern "C" void kernel_launch(void* const* d_in, const int* in_sizes, int n_in,
                              void* d_out, int out_size, void* d_ws, size_t ws_size,
                              hipStream_t stream)
{
  const float* x   = (const float*)d_in[0];
  const int*  ei   = (const int*)d_in[1];
  const int*  batch= (const int*)d_in[2];
  const float* Wq  = (const float*)d_in[3];
  const float* bq  = (const float*)d_in[4];
  const float* Wk  = (const float*)d_in[5];
  const float* bk  = (const float*)d_in[6];
  const float* Wv  = (const float*)d_in[7];
  const float* bv  = (const float*)d_in[8];
  const float* Ws  = (const float*)d_in[9];
  const float* bs  = (const float*)d_in[10];
  float* out = (float*)d_out;

  const int N = in_sizes[0] / D;   // 50000
  const int E = in_sizes[1] / 2;   // 800000
  const int* esrc = ei;
  const int* edst = ei + E;

  float* ws = (float*)d_ws;
  size_t off = 0;
  float* q    = ws + off; off += (size_t)N*D;
  float* k    = ws + off; off += (size_t)N*D;
  float* v    = ws + off; off += (size_t)N*D;
  float* sp   = ws + off; off += (size_t)N*D;   // s-proj in, relu(out) in-place
  // zero region: [deg | gsum | gcnt]
  int*   deg  = (int*)(ws + off);  off += N;
  float* gsum = ws + off; off += (size_t)NG*D;
  float* gcnt = ws + off; off += NG;
  int*   ptr  = (int*)(ws + off);  off += N;
  int*   cursor = (int*)(ws + off); off += N;
  int*   bsum = (int*)(ws + off);  off += 256;
  int*   boff = (int*)(ws + off);  off += 256;
  int*   csr_src = (int*)(ws + off); off += E;

  size_t zbytes = ((size_t)N + (size_t)NG*D + NG) * sizeof(float);
  hipMemsetAsync((void*)deg, 0, zbytes, stream);

  const int NB = (N + 255) / 256;

  k_linear4<<<1024, 256, 0, stream>>>(x, Wq,bq, Wk,bk, Wv,bv, Ws,bs, q,k,v,sp, N);
  k_hist <<<(E+255)/256, 256, 0, stream>>>(edst, deg, E);
  k_scan1<<<NB, 256, 0, stream>>>(deg, ptr, bsum, N);
  k_scan2<<<1, 256, 0, stream>>>(bsum, boff, NB);
  k_scan3<<<NB, 256, 0, stream>>>(ptr, boff, cursor, N);
  k_fill <<<(E+255)/256, 256, 0, stream>>>(esrc, edst, cursor, csr_src, E);
  k_attend<<<(N+3)/4, 256, 0, stream>>>(q, k, v, sp, ptr, deg, csr_src, N);
  const int rpw = 32;
  int nwaves = (N + rpw - 1) / rpw;
  k_pool<<<(nwaves+3)/4, 256, 0, stream>>>(sp, batch, gsum, gcnt, N, rpw);
  k_final<<<(NG*D+255)/256, 256, 0, stream>>>(gsum, gcnt, out, NG*D);
}